// Round 5
// baseline (187.270 us; speedup 1.0000x reference)
//
#include <hip/hip_runtime.h>

#define U_   2048
#define T_   200
#define S_   10
#define K_   20
#define H_   16
#define DU_  32
#define DE_  32
#define DIN_ 264   // 32 + 11 + 220 + 1

#define THREADS 256
#define TILE 256   // positions per block; thread t owns position tile+t

// async global->LDS, 16B per lane; HW dest = wave-uniform base + lane*16 (m104),
// so LDS layout is forced linear in granule id; all swizzling goes on the SOURCE.
__device__ __forceinline__ void g2l16(const void* g, void* l) {
    __builtin_amdgcn_global_load_lds(
        (const __attribute__((address_space(1))) void*)g,
        (__attribute__((address_space(3))) void*)l, 16, 0, 0);
}

// ---------------------------------------------------------------------------
// Kernel 1: pre[pos,h] = b_rnn[h] + x[pos,:] . Wx[:,h]
// f (bulk of HBM) staged through LDS in 13 column-chunks (12x16 + 1x8 floats),
// double-buffered, ONE barrier per chunk, prefetch issued before compute.
// Source pre-swizzled / read same-XOR (rule #21) -> b128 reads at bank floor.
// Weights via wave-uniform scalar loads (R4's proven path). q tile staged
// linearly (contiguous). emb/ct/docid direct.
// ---------------------------------------------------------------------------
__global__ __launch_bounds__(THREADS) void k_pre(
    const float* __restrict__ q, const float* __restrict__ f,
    const int* __restrict__ docid, const float* __restrict__ ct,
    const float* __restrict__ emb, const float* __restrict__ Wx,
    const float* __restrict__ brnn, float* __restrict__ pre)
{
    __shared__ __align__(16) float fbuf[2][TILE * 16];  // 2 x 16 KB
    __shared__ __align__(16) float qbuf[TILE * S_];     // 10 KB
    const int t = threadIdx.x;
    const int tile = blockIdx.x * TILE;                 // grid 1600 exact
    const int idx = tile + t;

    const char* fbase = (const char*)f + (size_t)tile * 800;

    // ---- prologue: stage f chunk 0 + whole q tile (async) ----
#pragma unroll
    for (int r = 0; r < 4; ++r) {
        int g = r * THREADS + t;                 // granule id = LDS slot (linear)
        int pos = g >> 2, s = g & 3;
        int sub = s ^ ((pos >> 1) & 3);          // source pre-swizzle
        g2l16(fbase + (size_t)pos * 800 + sub * 16, (char*)&fbuf[0][0] + g * 16);
    }
    {
        const char* qbase = (const char*)q + (size_t)tile * 40;  // contiguous tile
#pragma unroll
        for (int r = 0; r < 3; ++r) {
            int g = r * THREADS + t;
            if (g < 640) g2l16(qbase + (size_t)g * 16, (char*)qbuf + g * 16);
        }
    }

    float acc[H_];
#pragma unroll
    for (int h = 0; h < H_; ++h) acc[h] = brnn[h];   // uniform -> s_load

    // ---- emb part (Wx rows 0..31) + ctime (row 263): direct, overlaps staging ----
    {
        const float4* e4 = (const float4*)(emb + (size_t)docid[idx] * DE_);
#pragma unroll
        for (int r = 0; r < DE_ / 4; ++r) {
            float4 v = e4[r];
            const float* w = Wx + (r * 4) * H_;
#pragma unroll
            for (int h = 0; h < H_; ++h)
                acc[h] += v.x * w[h] + v.y * w[h + 16] + v.z * w[h + 32] + v.w * w[h + 48];
        }
        float c = ct[idx];
        const float* w = Wx + (DIN_ - 1) * H_;
#pragma unroll
        for (int h = 0; h < H_; ++h) acc[h] += c * w[h];
    }

    // ---- 13 f chunks: chunk c covers f-cols [16c,16c+16) -> Wx rows 43+16c.. ----
#pragma unroll 1
    for (int c = 0; c < 13; ++c) {
        __syncthreads();   // drains own-wave vmcnt -> chunk c (and q) resident;
                           // also: all readers of buf[(c+1)&1] (chunk c-1) are done.
        if (c < 11) {
            // prefetch full chunk c+1 (64B/pos), in flight during compute of c
            char* db = (char*)&fbuf[(c + 1) & 1][0];
#pragma unroll
            for (int r = 0; r < 4; ++r) {
                int g = r * THREADS + t;
                int pos = g >> 2, s = g & 3;
                int sub = s ^ ((pos >> 1) & 3);
                g2l16(fbase + (size_t)pos * 800 + (c + 1) * 64 + sub * 16, db + g * 16);
            }
        } else if (c == 11) {
            // prefetch tail chunk 12 (8 floats = 32B/pos, 2 granules)
            char* db = (char*)&fbuf[0][0];       // 12 & 1 == 0
#pragma unroll
            for (int r = 0; r < 2; ++r) {
                int g = r * THREADS + t;
                int pos = g >> 1, s = g & 1;
                int sub = s ^ ((pos >> 2) & 1);
                g2l16(fbase + (size_t)pos * 800 + 768 + sub * 16, db + g * 16);
            }
        }

        if (c < 12) {
            const float* base = &fbuf[c & 1][0];
            const float* wc = Wx + (43 + c * 16) * H_;   // uniform -> s_load
#pragma unroll
            for (int j = 0; j < 4; ++j) {
                int slot = j ^ ((t >> 1) & 3);           // same XOR as source
                float4 v = *(const float4*)(base + t * 16 + slot * 4);
                const float* w = wc + (4 * j) * H_;
#pragma unroll
                for (int h = 0; h < H_; ++h)
                    acc[h] += v.x * w[h] + v.y * w[h + 16] + v.z * w[h + 32] + v.w * w[h + 48];
            }
        } else {
            const float* base = &fbuf[0][0];
            const float* wc = Wx + (43 + 192) * H_;
#pragma unroll
            for (int j = 0; j < 2; ++j) {
                int slot = j ^ ((t >> 2) & 1);
                float4 v = *(const float4*)(base + t * 8 + slot * 4);
                const float* w = wc + (4 * j) * H_;
#pragma unroll
                for (int h = 0; h < H_; ++h)
                    acc[h] += v.x * w[h] + v.y * w[h + 16] + v.z * w[h + 32] + v.w * w[h + 48];
            }
        }
    }

    // ---- q part (Wx rows 32..41): qbuf staged at prologue, still intact ----
    {
        const float* xq = qbuf + t * S_;
#pragma unroll
        for (int r = 0; r < S_ / 2; ++r) {
            float2 v = *(const float2*)(xq + 2 * r);
            const float* w = Wx + (DE_ + 2 * r) * H_;
#pragma unroll
            for (int h = 0; h < H_; ++h)
                acc[h] += v.x * w[h] + v.y * w[h + 16];
        }
    }

    // ---- store ----
    float4* o = (float4*)(pre + (size_t)idx * H_);
    o[0] = make_float4(acc[0], acc[1], acc[2], acc[3]);
    o[1] = make_float4(acc[4], acc[5], acc[6], acc[7]);
    o[2] = make_float4(acc[8], acc[9], acc[10], acc[11]);
    o[3] = make_float4(acc[12], acc[13], acc[14], acc[15]);
}

// ---------------------------------------------------------------------------
// Kernel 2: sequential RNN scan per user (16 lanes = 16 h-components),
// fused LeakyReLU + Dense(32).  (unchanged)
// ---------------------------------------------------------------------------
__device__ __forceinline__ float tanh_fast(float x) {
    float e = __expf(2.f * x);
    return 1.f - 2.f / (e + 1.f);
}

__global__ __launch_bounds__(64) void k_rnn(
    const float* __restrict__ pre, const int* __restrict__ docid,
    const float* __restrict__ Wh, const float* __restrict__ Wd,
    const float* __restrict__ bd, float* __restrict__ out)
{
    const int tid = threadIdx.x;
    const int l = tid & 15;
    const int u = (blockIdx.x * 64 + tid) >> 4;

    const float* prow = pre + (size_t)u * T_ * H_;
    const int* drow = docid + (size_t)u * T_;

    float wh[16];
#pragma unroll
    for (int k = 0; k < 16; ++k) wh[k] = Wh[((l ^ k) << 4) | l];

    float h = 0.f;

    float pb0 = prow[0 * H_ + l], pb1 = prow[1 * H_ + l],
          pb2 = prow[2 * H_ + l], pb3 = prow[3 * H_ + l];
    int   m0 = drow[0], m1 = drow[1], m2 = drow[2], m3 = drow[3];

    for (int tb = 0; tb < T_; tb += 4) {
#pragma unroll
        for (int s = 0; s < 4; ++s) {
            float p; int m;
            if      (s == 0) { p = pb0; m = m0; }
            else if (s == 1) { p = pb1; m = m1; }
            else if (s == 2) { p = pb2; m = m2; }
            else             { p = pb3; m = m3; }

            int tn = tb + 4 + s; if (tn > T_ - 1) tn = T_ - 1;
            float pn = prow[tn * H_ + l];
            int   mn = drow[tn];
            if      (s == 0) { pb0 = pn; m0 = mn; }
            else if (s == 1) { pb1 = pn; m1 = mn; }
            else if (s == 2) { pb2 = pn; m2 = mn; }
            else             { pb3 = pn; m3 = mn; }

            float a0 = p, a1 = 0.f, a2 = 0.f, a3 = 0.f;
#pragma unroll
            for (int k = 0; k < 16; k += 4) {
                a0 += __shfl_xor(h, k + 0, 16) * wh[k + 0];
                a1 += __shfl_xor(h, k + 1, 16) * wh[k + 1];
                a2 += __shfl_xor(h, k + 2, 16) * wh[k + 2];
                a3 += __shfl_xor(h, k + 3, 16) * wh[k + 3];
            }
            float accv = (a0 + a1) + (a2 + a3);
            float th = tanh_fast(accv);
            h = (m != 0) ? th : h;
        }
    }

    float a = (h >= 0.f) ? h : 0.3f * h;

    float wd0[16], wd1[16];
#pragma unroll
    for (int k = 0; k < 16; ++k) {
        int j = l ^ k;
        wd0[k] = Wd[j * DU_ + l];
        wd1[k] = Wd[j * DU_ + l + 16];
    }
    float o0 = bd[l], o1 = bd[l + 16];
#pragma unroll
    for (int k = 0; k < 16; ++k) {
        float av = __shfl_xor(a, k, 16);
        o0 += av * wd0[k];
        o1 += av * wd1[k];
    }
    out[(size_t)u * DU_ + l] = o0;
    out[(size_t)u * DU_ + l + 16] = o1;
}

// ---------------------------------------------------------------------------
extern "C" void kernel_launch(void* const* d_in, const int* in_sizes, int n_in,
                              void* d_out, int out_size, void* d_ws, size_t ws_size,
                              hipStream_t stream) {
    const float* q     = (const float*)d_in[0];
    const float* f     = (const float*)d_in[1];
    const int*   docid = (const int*)  d_in[2];
    const float* ct    = (const float*)d_in[3];
    const float* emb   = (const float*)d_in[4];
    const float* Wx    = (const float*)d_in[5];
    const float* Wh    = (const float*)d_in[6];
    const float* brnn  = (const float*)d_in[7];
    const float* Wd    = (const float*)d_in[8];
    const float* bd    = (const float*)d_in[9];
    float* out = (float*)d_out;

    float* pre = (float*)d_ws;                   // U*T*H floats = 26.2 MB

    k_pre<<<(U_ * T_) / TILE, THREADS, 0, stream>>>(q, f, docid, ct, emb, Wx, brnn, pre);
    k_rnn<<<(U_ * H_) / 64, 64, 0, stream>>>(pre, docid, Wh, Wd, bd, out);
}